// Round 11
// baseline (476.607 us; speedup 1.0000x reference)
//
#include <hip/hip_runtime.h>

#define DIM  128
#define BINS 1024

typedef __attribute__((ext_vector_type(8))) _Float16 f16x8;
typedef __attribute__((ext_vector_type(4))) float f32x4;

#define MFMA16(a, b, c) __builtin_amdgcn_mfma_f32_16x16x32_f16(a, b, c, 0, 0, 0)

#define GLDS(gp, lp) __builtin_amdgcn_global_load_lds(                        \
    (const __attribute__((address_space(1))) void*)(gp),                     \
    (__attribute__((address_space(3))) void*)(lp), 16, 0, 0)

// branchless top-4 insert, strict > (first-wins with ascending insert order)
__device__ __forceinline__ void ins4(float d, int b,
    float& d0, int& b0, float& d1, int& b1,
    float& d2, int& b2, float& d3, int& b3)
{
    bool g0 = d > d0, g1 = d > d1, g2 = d > d2, g3 = d > d3;
    float nd3 = g2 ? d2 : (g3 ? d : d3); int nb3 = g2 ? b2 : (g3 ? b : b3);
    float nd2 = g1 ? d1 : (g2 ? d : d2); int nb2 = g1 ? b1 : (g2 ? b : b2);
    float nd1 = g0 ? d0 : (g1 ? d : d1); int nb1 = g0 ? b0 : (g1 ? b : b1);
    float nd0 = g0 ? d  : d0;            int nb0 = g0 ? b  : b0;
    d0 = nd0; b0 = nb0; d1 = nd1; b1 = nb1;
    d2 = nd2; b2 = nb2; d3 = nd3; b3 = nb3;
}

// ---- prep: esq (round-1 1-chain fmaf, exact fp32) + E -> swizzled fp16 ----
__global__ __launch_bounds__(256) void vq_prep(
    const float* __restrict__ embed, _Float16* __restrict__ ehs,
    float* __restrict__ esq_g)
{
    int b = blockIdx.x * 256 + threadIdx.x;  // grid exactly BINS/256
    const float* e = embed + (size_t)b * DIM;
    float s = 0.f;
    #pragma unroll
    for (int k = 0; k < DIM; ++k) s = fmaf(e[k], e[k], s);
    esq_g[b] = s;
    #pragma unroll
    for (int c = 0; c < 16; ++c) {          // 16B chunks of the fp16 row
        int slot = c ^ (b & 15);            // XOR-swizzle baked into storage
        #pragma unroll
        for (int j = 0; j < 8; ++j)
            ehs[b * 128 + slot * 8 + j] = (_Float16)e[c * 8 + j];   // RNE
    }
}

// ---- stage A: 1-term fp16 MFMA approx + per-row top-4 quad candidates ----
// 256 thr = 4 waves (4 blocks/CU at 36 KB LDS); wave owns 32 rows (2 rowsets).
// Swapped GEMM: A = E (16 bins x 32 k), B = X^T. D: col(lane&15)=x-row,
// row((lane>>4)*4+reg)=bin. key = 2*dot_h - esq (monotone in -dist).
__global__ __launch_bounds__(256) void vq_stage_a(
    const float* __restrict__ x,
    const _Float16* __restrict__ ehs_g,
    const float* __restrict__ esq_g,
    float* __restrict__ cand)               // [N][4] candidate quad bases
{
    __shared__ _Float16 ehb[2][8192];       // 2 x 16 KB (64 bins x 128 fp16)
    __shared__ float esq_lds[BINS];         // 4 KB

    const int tid = threadIdx.x;
    const int li  = tid & 15;
    const int g   = (tid >> 4) & 3;
    const int w   = tid >> 6;

    // X fragments fp16 (rows rowA, rowA+16) — 32 VGPR, const-indexed
    f16x8 xh[2][4];
    const size_t rowA = (size_t)blockIdx.x * 128 + w * 32 + li;
    #pragma unroll
    for (int rs = 0; rs < 2; ++rs) {
        const float* xp = x + (rowA + rs * 16) * DIM + g * 8;
        #pragma unroll
        for (int s = 0; s < 4; ++s) {
            float4 v0 = *(const float4*)(xp + s * 32);
            float4 v1 = *(const float4*)(xp + s * 32 + 4);
            f16x8 h;
            h[0] = (_Float16)v0.x; h[1] = (_Float16)v0.y;
            h[2] = (_Float16)v0.z; h[3] = (_Float16)v0.w;
            h[4] = (_Float16)v1.x; h[5] = (_Float16)v1.y;
            h[6] = (_Float16)v1.z; h[7] = (_Float16)v1.w;
            xh[rs][s] = h;
        }
    }

    // staging: 16 KB slab by 256 threads = 4 GLDS x 16B
#define STAGE(stp_, buf_) do {                                                \
        const char* gE_ = (const char*)ehs_g + (size_t)(stp_) * 16384;        \
        char* lE_ = (char*)&ehb[buf_][0];                                     \
        _Pragma("unroll")                                                     \
        for (int j_ = 0; j_ < 4; ++j_) {                                      \
            int o_ = tid * 16 + j_ * 4096;                                    \
            GLDS(gE_ + o_, lE_ + o_);                                         \
        }                                                                     \
    } while (0)

    // ---- prologue: esq + slab 0 ----
    GLDS((const char*)esq_g + tid * 16, (char*)esq_lds + tid * 16);
    STAGE(0, 0);
    asm volatile("s_waitcnt vmcnt(0)" ::: "memory");
    __syncthreads();

    float d0[2], d1[2], d2[2], d3[2];
    int   b0[2], b1[2], b2[2], b3[2];
    #pragma unroll
    for (int rs = 0; rs < 2; ++rs) {
        d0[rs] = d1[rs] = d2[rs] = d3[rs] = -3.402823466e38f;
        b0[rs] = b1[rs] = b2[rs] = b3[rs] = 0;
    }

    // fragment address: row (tl*16+li) at tl*4096B... (fp16: row stride 256 B),
    // chunk (g+4s) at slot ((g+4s)^li)*16B (matches prep's c ^ (b&15))
#define LDE(tl_, s_) (*(const f16x8*)((const char*)&ehb[buf][0] + (tl_) * 4096 + li * 256 + (((g + 4 * (s_)) ^ li) << 4)))

    for (int stp = 0; stp < 16; ++stp) {     // 16 steps x 64 bins
        const int buf = stp & 1;
        if (stp < 15) STAGE(stp + 1, buf ^ 1);   // prefetch next 64-bin slab

        #pragma unroll
        for (int tl = 0; tl < 4; ++tl) {
            f32x4 aP0 = {0.f,0.f,0.f,0.f}, aP1 = {0.f,0.f,0.f,0.f};
            f16x8 eh0 = LDE(tl, 0), eh1 = LDE(tl, 1);
            f16x8 eh2 = LDE(tl, 2), eh3 = LDE(tl, 3);
            aP0 = MFMA16(eh0, xh[0][0], aP0); aP1 = MFMA16(eh0, xh[1][0], aP1);
            aP0 = MFMA16(eh1, xh[0][1], aP0); aP1 = MFMA16(eh1, xh[1][1], aP1);
            aP0 = MFMA16(eh2, xh[0][2], aP0); aP1 = MFMA16(eh2, xh[1][2], aP1);
            aP0 = MFMA16(eh3, xh[0][3], aP0); aP1 = MFMA16(eh3, xh[1][3], aP1);
            // quad fold: key = 2*dot - esq; quad max tree + one ins4
            const int binb = stp * 64 + tl * 16 + g * 4;   // quad base
            const f32x4 eq = *(const f32x4*)&esq_lds[binb];
            {
                float k0 = fmaf(2.f, aP0[0], -eq[0]);
                float k1 = fmaf(2.f, aP0[1], -eq[1]);
                float k2 = fmaf(2.f, aP0[2], -eq[2]);
                float k3 = fmaf(2.f, aP0[3], -eq[3]);
                float gm = fmaxf(fmaxf(k0, k1), fmaxf(k2, k3));
                ins4(gm, binb, d0[0], b0[0], d1[0], b1[0],
                               d2[0], b2[0], d3[0], b3[0]);
            }
            {
                float k0 = fmaf(2.f, aP1[0], -eq[0]);
                float k1 = fmaf(2.f, aP1[1], -eq[1]);
                float k2 = fmaf(2.f, aP1[2], -eq[2]);
                float k3 = fmaf(2.f, aP1[3], -eq[3]);
                float gm = fmaxf(fmaxf(k0, k1), fmaxf(k2, k3));
                ins4(gm, binb, d0[1], b0[1], d1[1], b1[1],
                               d2[1], b2[1], d3[1], b3[1]);
            }
        }
        asm volatile("s_waitcnt vmcnt(0)" ::: "memory");
        __syncthreads();
    }
#undef LDE
#undef STAGE

    // ---- merge the 4 k-groups (disjoint quad sets, same rows) ----
    #pragma unroll
    for (int mm = 16; mm <= 32; mm <<= 1) {
        #pragma unroll
        for (int rs = 0; rs < 2; ++rs) {
            float pd0 = __shfl_xor(d0[rs], mm); int pb0 = __shfl_xor(b0[rs], mm);
            float pd1 = __shfl_xor(d1[rs], mm); int pb1 = __shfl_xor(b1[rs], mm);
            float pd2 = __shfl_xor(d2[rs], mm); int pb2 = __shfl_xor(b2[rs], mm);
            float pd3 = __shfl_xor(d3[rs], mm); int pb3 = __shfl_xor(b3[rs], mm);
            ins4(pd0, pb0, d0[rs], b0[rs], d1[rs], b1[rs], d2[rs], b2[rs], d3[rs], b3[rs]);
            ins4(pd1, pb1, d0[rs], b0[rs], d1[rs], b1[rs], d2[rs], b2[rs], d3[rs], b3[rs]);
            ins4(pd2, pb2, d0[rs], b0[rs], d1[rs], b1[rs], d2[rs], b2[rs], d3[rs], b3[rs]);
            ins4(pd3, pb3, d0[rs], b0[rs], d1[rs], b1[rs], d2[rs], b2[rs], d3[rs], b3[rs]);
        }
    }
    if ((tid & 63) < 16) {
        #pragma unroll
        for (int rs = 0; rs < 2; ++rs) {
            const size_t r = rowA + rs * 16;
            cand[r * 4 + 0] = (float)b0[rs];
            cand[r * 4 + 1] = (float)b1[rs];
            cand[r * 4 + 2] = (float)b2[rs];
            cand[r * 4 + 3] = (float)b3[rs];
        }
    }
}

// ---- rescore: exact fp32, 4 lanes/row, one quad (4 bins) per lane ----
// Per-bin chain = k mod 4 + (a0+a1)+(a2+a3), xsq single chain k ascending:
// structure identical to the round-10-proven kernel. No LDS, coalesced x.
__global__ __launch_bounds__(256) void vq_rescore(
    const float* __restrict__ x, const float* __restrict__ embed,
    const float* __restrict__ esq_g, const float* __restrict__ cand,
    float* __restrict__ ind_f)
{
    const int tid  = threadIdx.x;
    const int lane = tid & 63;
    const int sub  = tid & 3;
    const size_t row = (size_t)blockIdx.x * 64 + (tid >> 2);

    // my quarter of the row (coalesced float4)
    const float4* xg = (const float4*)(x + row * DIM);
    float4 xq[8];
    #pragma unroll
    for (int j = 0; j < 8; ++j) xq[j] = xg[sub * 8 + j];

    const int qb = (int)cand[row * 4 + sub];   // this lane's quad base

    const float4* e4 = (const float4*)embed;
    f32x4 accA = {0.f,0.f,0.f,0.f}, accB = {0.f,0.f,0.f,0.f};
    f32x4 accC = {0.f,0.f,0.f,0.f}, accD = {0.f,0.f,0.f,0.f};
    float xs = 0.f;
    #pragma unroll 8
    for (int q = 0; q < 32; ++q) {
        const int src = (lane & ~3) | (q >> 3);
        float4 xv;
        xv.x = __shfl(xq[q & 7].x, src);
        xv.y = __shfl(xq[q & 7].y, src);
        xv.z = __shfl(xq[q & 7].z, src);
        xv.w = __shfl(xq[q & 7].w, src);
        xs = fmaf(xv.x, xv.x, xs); xs = fmaf(xv.y, xv.y, xs);
        xs = fmaf(xv.z, xv.z, xs); xs = fmaf(xv.w, xv.w, xs);
        float4 eA = e4[(size_t)(qb + 0) * 32 + q];
        float4 eB = e4[(size_t)(qb + 1) * 32 + q];
        float4 eC = e4[(size_t)(qb + 2) * 32 + q];
        float4 eD = e4[(size_t)(qb + 3) * 32 + q];
        accA[0] = fmaf(xv.x, eA.x, accA[0]); accA[1] = fmaf(xv.y, eA.y, accA[1]);
        accA[2] = fmaf(xv.z, eA.z, accA[2]); accA[3] = fmaf(xv.w, eA.w, accA[3]);
        accB[0] = fmaf(xv.x, eB.x, accB[0]); accB[1] = fmaf(xv.y, eB.y, accB[1]);
        accB[2] = fmaf(xv.z, eB.z, accB[2]); accB[3] = fmaf(xv.w, eB.w, accB[3]);
        accC[0] = fmaf(xv.x, eC.x, accC[0]); accC[1] = fmaf(xv.y, eC.y, accC[1]);
        accC[2] = fmaf(xv.z, eC.z, accC[2]); accC[3] = fmaf(xv.w, eC.w, accC[3]);
        accD[0] = fmaf(xv.x, eD.x, accD[0]); accD[1] = fmaf(xv.y, eD.y, accD[1]);
        accD[2] = fmaf(xv.z, eD.z, accD[2]); accD[3] = fmaf(xv.w, eD.w, accD[3]);
    }
    float bd = -3.402823466e38f;
    int   bb = 0x7FFFFFFF;
    #pragma unroll
    for (int c = 0; c < 4; ++c) {
        const f32x4& ac = (c == 0) ? accA : (c == 1) ? accB : (c == 2) ? accC : accD;
        const int b = qb + c;
        float dot = (ac[0] + ac[1]) + (ac[2] + ac[3]);
        float d = -(fmaf(-2.f, dot, xs) + esq_g[b]);   // round-1 expression
        if (d > bd || (d == bd && b < bb)) { bd = d; bb = b; }
    }
    #pragma unroll
    for (int m = 1; m <= 2; m <<= 1) {      // quad-local (d, bin) argmax
        float pd = __shfl_xor(bd, m);
        int   pb = __shfl_xor(bb, m);
        if (pd > bd || (pd == bd && pb < bb)) { bd = pd; bb = pb; }
    }
    if (sub == 0) ind_f[row] = (float)bb;
}

// ---- gather: quantize = embed[ind], coalesced float4 ----
__global__ __launch_bounds__(256) void vq_gather(
    const float* __restrict__ embed,
    const float* __restrict__ ind_f,
    float4* __restrict__ out)
{
    int i   = blockIdx.x * 256 + threadIdx.x;   // over N*DIM/4
    int row = i >> 5;                           // DIM/4 == 32
    int k   = i & 31;
    int b   = (int)ind_f[row];
    out[i] = reinterpret_cast<const float4*>(embed)[b * (DIM / 4) + k];
}

extern "C" void kernel_launch(void* const* d_in, const int* in_sizes, int n_in,
                              void* d_out, int out_size, void* d_ws, size_t ws_size,
                              hipStream_t stream) {
    const float* x     = (const float*)d_in[0];   // [N, 128] fp32
    const float* embed = (const float*)d_in[1];   // [1024, 128] fp32
    float* out = (float*)d_out;

    const int N = in_sizes[0] / DIM;              // 262144
    float* ind_f = out + (size_t)N * DIM;         // output 1 (indices as float)

    // scratch carved out of the quantize region (fully overwritten by gather):
    char* ob = (char*)d_out;
    float* cand = out;                                        // [N][4] floats (4 MB)
    _Float16* ehs = (_Float16*)(ob + (32u << 20));            // 256 KB fp16 table
    float* esq_g  = (float*)(ob + (36u << 20));               // 4 KB

    vq_prep<<<BINS / 256, 256, 0, stream>>>(embed, ehs, esq_g);
    vq_stage_a<<<N / 128, 256, 0, stream>>>(x, ehs, esq_g, cand);
    vq_rescore<<<N / 64, 256, 0, stream>>>(x, embed, esq_g, cand, ind_f);
    vq_gather<<<(N * (DIM / 4)) / 256, 256, 0, stream>>>(embed, ind_f, (float4*)out);
}

// Round 12
// 217.084 us; speedup vs baseline: 2.1955x; 2.1955x over previous
//
#include <hip/hip_runtime.h>

#define DIM  128
#define BINS 1024

typedef __attribute__((ext_vector_type(8))) _Float16 f16x8;
typedef __attribute__((ext_vector_type(4))) float f32x4;

#define MFMA16(a, b, c) __builtin_amdgcn_mfma_f32_16x16x32_f16(a, b, c, 0, 0, 0)

#define GLDS(gp, lp) __builtin_amdgcn_global_load_lds(                        \
    (const __attribute__((address_space(1))) void*)(gp),                     \
    (__attribute__((address_space(3))) void*)(lp), 16, 0, 0)

// branchless top-4 insert, strict > (first-wins with ascending insert order)
__device__ __forceinline__ void ins4(float d, int b,
    float& d0, int& b0, float& d1, int& b1,
    float& d2, int& b2, float& d3, int& b3)
{
    bool g0 = d > d0, g1 = d > d1, g2 = d > d2, g3 = d > d3;
    float nd3 = g2 ? d2 : (g3 ? d : d3); int nb3 = g2 ? b2 : (g3 ? b : b3);
    float nd2 = g1 ? d1 : (g2 ? d : d2); int nb2 = g1 ? b1 : (g2 ? b : b2);
    float nd1 = g0 ? d0 : (g1 ? d : d1); int nb1 = g0 ? b0 : (g1 ? b : b1);
    float nd0 = g0 ? d  : d0;            int nb0 = g0 ? b  : b0;
    d0 = nd0; b0 = nb0; d1 = nd1; b1 = nb1;
    d2 = nd2; b2 = nb2; d3 = nd3; b3 = nb3;
}

// ---- prep: esq (round-1 1-chain fmaf, exact fp32) + E -> swizzled fp16 ----
__global__ __launch_bounds__(256) void vq_prep(
    const float* __restrict__ embed, _Float16* __restrict__ ehs,
    float* __restrict__ esq_g)
{
    int b = blockIdx.x * 256 + threadIdx.x;  // grid exactly BINS/256
    const float* e = embed + (size_t)b * DIM;
    float s = 0.f;
    #pragma unroll
    for (int k = 0; k < DIM; ++k) s = fmaf(e[k], e[k], s);
    esq_g[b] = s;
    #pragma unroll
    for (int c = 0; c < 16; ++c) {          // 16B chunks of the fp16 row
        int slot = c ^ (b & 15);            // XOR-swizzle baked into storage
        #pragma unroll
        for (int j = 0; j < 8; ++j)
            ehs[b * 128 + slot * 8 + j] = (_Float16)e[c * 8 + j];   // RNE
    }
}

// ---- stage A: 1-term fp16 MFMA approx + per-row top-4 PAIR candidates ----
// 256 thr = 4 waves; wave owns 32 rows (2 rowsets). Swapped GEMM.
// D: col(lane&15)=x-row, row((lane>>4)*4+reg)=bin. key = 2*dot_h - esq.
__global__ __launch_bounds__(256) void vq_stage_a(
    const float* __restrict__ x,
    const _Float16* __restrict__ ehs_g,
    const float* __restrict__ esq_g,
    float* __restrict__ cand)               // [N][4] candidate PAIR bases
{
    __shared__ _Float16 ehb[2][8192];       // 2 x 16 KB (64 bins x 128 fp16)
    __shared__ float esq_lds[BINS];         // 4 KB

    const int tid = threadIdx.x;
    const int li  = tid & 15;
    const int g   = (tid >> 4) & 3;
    const int w   = tid >> 6;

    // X fragments fp16 (rows rowA, rowA+16) — 32 VGPR, const-indexed
    f16x8 xh[2][4];
    const size_t rowA = (size_t)blockIdx.x * 128 + w * 32 + li;
    #pragma unroll
    for (int rs = 0; rs < 2; ++rs) {
        const float* xp = x + (rowA + rs * 16) * DIM + g * 8;
        #pragma unroll
        for (int s = 0; s < 4; ++s) {
            float4 v0 = *(const float4*)(xp + s * 32);
            float4 v1 = *(const float4*)(xp + s * 32 + 4);
            f16x8 h;
            h[0] = (_Float16)v0.x; h[1] = (_Float16)v0.y;
            h[2] = (_Float16)v0.z; h[3] = (_Float16)v0.w;
            h[4] = (_Float16)v1.x; h[5] = (_Float16)v1.y;
            h[6] = (_Float16)v1.z; h[7] = (_Float16)v1.w;
            xh[rs][s] = h;
        }
    }

#define STAGE(stp_, buf_) do {                                                \
        const char* gE_ = (const char*)ehs_g + (size_t)(stp_) * 16384;        \
        char* lE_ = (char*)&ehb[buf_][0];                                     \
        _Pragma("unroll")                                                     \
        for (int j_ = 0; j_ < 4; ++j_) {                                      \
            int o_ = tid * 16 + j_ * 4096;                                    \
            GLDS(gE_ + o_, lE_ + o_);                                         \
        }                                                                     \
    } while (0)

    // ---- prologue: esq + slab 0 ----
    GLDS((const char*)esq_g + tid * 16, (char*)esq_lds + tid * 16);
    STAGE(0, 0);
    asm volatile("s_waitcnt vmcnt(0)" ::: "memory");
    __syncthreads();

    float d0[2], d1[2], d2[2], d3[2];
    int   b0[2], b1[2], b2[2], b3[2];
    #pragma unroll
    for (int rs = 0; rs < 2; ++rs) {
        d0[rs] = d1[rs] = d2[rs] = d3[rs] = -3.402823466e38f;
        b0[rs] = b1[rs] = b2[rs] = b3[rs] = 0;
    }

#define LDE(tl_, s_) (*(const f16x8*)((const char*)&ehb[buf][0] + (tl_) * 4096 + li * 256 + (((g + 4 * (s_)) ^ li) << 4)))

    for (int stp = 0; stp < 16; ++stp) {     // 16 steps x 64 bins
        const int buf = stp & 1;
        if (stp < 15) STAGE(stp + 1, buf ^ 1);   // prefetch next 64-bin slab

        #pragma unroll
        for (int tl = 0; tl < 4; ++tl) {
            f32x4 aP0 = {0.f,0.f,0.f,0.f}, aP1 = {0.f,0.f,0.f,0.f};
            f16x8 eh0 = LDE(tl, 0), eh1 = LDE(tl, 1);
            f16x8 eh2 = LDE(tl, 2), eh3 = LDE(tl, 3);
            aP0 = MFMA16(eh0, xh[0][0], aP0); aP1 = MFMA16(eh0, xh[1][0], aP1);
            aP0 = MFMA16(eh1, xh[0][1], aP0); aP1 = MFMA16(eh1, xh[1][1], aP1);
            aP0 = MFMA16(eh2, xh[0][2], aP0); aP1 = MFMA16(eh2, xh[1][2], aP1);
            aP0 = MFMA16(eh3, xh[0][3], aP0); aP1 = MFMA16(eh3, xh[1][3], aP1);
            // pair fold: key = 2*dot - esq; pair max + two ins4
            const int binb = stp * 64 + tl * 16 + g * 4;   // quad base
            const f32x4 eq = *(const f32x4*)&esq_lds[binb];
            {
                float k0 = fmaf(2.f, aP0[0], -eq[0]);
                float k1 = fmaf(2.f, aP0[1], -eq[1]);
                float k2 = fmaf(2.f, aP0[2], -eq[2]);
                float k3 = fmaf(2.f, aP0[3], -eq[3]);
                float pm01 = fmaxf(k0, k1), pm23 = fmaxf(k2, k3);
                ins4(pm01, binb,     d0[0], b0[0], d1[0], b1[0],
                                     d2[0], b2[0], d3[0], b3[0]);
                ins4(pm23, binb + 2, d0[0], b0[0], d1[0], b1[0],
                                     d2[0], b2[0], d3[0], b3[0]);
            }
            {
                float k0 = fmaf(2.f, aP1[0], -eq[0]);
                float k1 = fmaf(2.f, aP1[1], -eq[1]);
                float k2 = fmaf(2.f, aP1[2], -eq[2]);
                float k3 = fmaf(2.f, aP1[3], -eq[3]);
                float pm01 = fmaxf(k0, k1), pm23 = fmaxf(k2, k3);
                ins4(pm01, binb,     d0[1], b0[1], d1[1], b1[1],
                                     d2[1], b2[1], d3[1], b3[1]);
                ins4(pm23, binb + 2, d0[1], b0[1], d1[1], b1[1],
                                     d2[1], b2[1], d3[1], b3[1]);
            }
        }
        asm volatile("s_waitcnt vmcnt(0)" ::: "memory");
        __syncthreads();
    }
#undef LDE
#undef STAGE

    // ---- merge the 4 k-groups (disjoint pair sets, same rows) ----
    #pragma unroll
    for (int mm = 16; mm <= 32; mm <<= 1) {
        #pragma unroll
        for (int rs = 0; rs < 2; ++rs) {
            float pd0 = __shfl_xor(d0[rs], mm); int pb0 = __shfl_xor(b0[rs], mm);
            float pd1 = __shfl_xor(d1[rs], mm); int pb1 = __shfl_xor(b1[rs], mm);
            float pd2 = __shfl_xor(d2[rs], mm); int pb2 = __shfl_xor(b2[rs], mm);
            float pd3 = __shfl_xor(d3[rs], mm); int pb3 = __shfl_xor(b3[rs], mm);
            ins4(pd0, pb0, d0[rs], b0[rs], d1[rs], b1[rs], d2[rs], b2[rs], d3[rs], b3[rs]);
            ins4(pd1, pb1, d0[rs], b0[rs], d1[rs], b1[rs], d2[rs], b2[rs], d3[rs], b3[rs]);
            ins4(pd2, pb2, d0[rs], b0[rs], d1[rs], b1[rs], d2[rs], b2[rs], d3[rs], b3[rs]);
            ins4(pd3, pb3, d0[rs], b0[rs], d1[rs], b1[rs], d2[rs], b2[rs], d3[rs], b3[rs]);
        }
    }
    if ((tid & 63) < 16) {
        #pragma unroll
        for (int rs = 0; rs < 2; ++rs) {
            const size_t r = rowA + rs * 16;
            cand[r * 4 + 0] = (float)b0[rs];
            cand[r * 4 + 1] = (float)b1[rs];
            cand[r * 4 + 2] = (float)b2[rs];
            cand[r * 4 + 3] = (float)b3[rs];
        }
    }
}

// ---- rescore: exact fp32 on 4 pairs (8 bins); k split across 4 lanes ----
// Lane sub owns k-chunks (j*4+sub)*4..+3 -> every e/x load is 64B-contiguous
// per 4-lane row-group. Butterfly shfl_xor sums are bitwise lane-identical.
// Optionally fuses the gather (outq != nullptr).
__global__ __launch_bounds__(256) void vq_rescore(
    const float* __restrict__ x, const float* __restrict__ embed,
    const float* __restrict__ esq_g, const float* __restrict__ cand,
    float* __restrict__ ind_f, float4* __restrict__ outq)
{
    const int tid = threadIdx.x;
    const int sub = tid & 3;
    const size_t row = (size_t)blockIdx.x * 64 + (tid >> 2);

    const float4* xg = (const float4*)(x + row * DIM);
    float4 xq[8];
    #pragma unroll
    for (int j = 0; j < 8; ++j) xq[j] = xg[j * 4 + sub];   // 64B/row-group

    float xs = 0.f;
    #pragma unroll
    for (int j = 0; j < 8; ++j) {
        float4 v = xq[j];
        xs = fmaf(v.x, v.x, xs); xs = fmaf(v.y, v.y, xs);
        xs = fmaf(v.z, v.z, xs); xs = fmaf(v.w, v.w, xs);
    }
    xs += __shfl_xor(xs, 1);
    xs += __shfl_xor(xs, 2);

    const float4 qv = *(const float4*)&cand[row * 4];
    const int qb0 = (int)qv.x, qb1 = (int)qv.y, qb2 = (int)qv.z, qb3 = (int)qv.w;

    const float4* e4 = (const float4*)embed;
    f32x4 acc[8];
    #pragma unroll
    for (int c = 0; c < 8; ++c) acc[c] = f32x4{0.f,0.f,0.f,0.f};
    #pragma unroll
    for (int c = 0; c < 8; ++c) {           // all 64 loads independent
        const int bin = (c < 2 ? qb0 : c < 4 ? qb1 : c < 6 ? qb2 : qb3) + (c & 1);
        #pragma unroll
        for (int j = 0; j < 8; ++j) {
            float4 ev = e4[(size_t)bin * 32 + j * 4 + sub];
            float4 xv = xq[j];
            acc[c][0] = fmaf(xv.x, ev.x, acc[c][0]);
            acc[c][1] = fmaf(xv.y, ev.y, acc[c][1]);
            acc[c][2] = fmaf(xv.z, ev.z, acc[c][2]);
            acc[c][3] = fmaf(xv.w, ev.w, acc[c][3]);
        }
    }
    float bd = -3.402823466e38f;
    int   bb = 0x7FFFFFFF;
    #pragma unroll
    for (int c = 0; c < 8; ++c) {
        const int bin = (c < 2 ? qb0 : c < 4 ? qb1 : c < 6 ? qb2 : qb3) + (c & 1);
        float p = (acc[c][0] + acc[c][1]) + (acc[c][2] + acc[c][3]);
        p += __shfl_xor(p, 1);
        p += __shfl_xor(p, 2);               // full dot, lane-identical
        float d = -(fmaf(-2.f, p, xs) + esq_g[bin]);   // round-1 expression
        if (d > bd || (d == bd && bin < bb)) { bd = d; bb = bin; }
    }
    if (sub == 0) ind_f[row] = (float)bb;
    if (outq) {                              // fused gather (all lanes agree on bb)
        #pragma unroll
        for (int j = 0; j < 8; ++j)
            outq[row * 32 + j * 4 + sub] = e4[(size_t)bb * 32 + j * 4 + sub];
    }
}

// ---- gather (fallback path only): quantize = embed[ind] ----
__global__ __launch_bounds__(256) void vq_gather(
    const float* __restrict__ embed,
    const float* __restrict__ ind_f,
    float4* __restrict__ out)
{
    int i   = blockIdx.x * 256 + threadIdx.x;   // over N*DIM/4
    int row = i >> 5;                           // DIM/4 == 32
    int k   = i & 31;
    int b   = (int)ind_f[row];
    out[i] = reinterpret_cast<const float4*>(embed)[b * (DIM / 4) + k];
}

extern "C" void kernel_launch(void* const* d_in, const int* in_sizes, int n_in,
                              void* d_out, int out_size, void* d_ws, size_t ws_size,
                              hipStream_t stream) {
    const float* x     = (const float*)d_in[0];   // [N, 128] fp32
    const float* embed = (const float*)d_in[1];   // [1024, 128] fp32
    float* out = (float*)d_out;

    const int N = in_sizes[0] / DIM;              // 262144
    float* ind_f = out + (size_t)N * DIM;         // output 1 (indices as float)

    const bool use_ws = ws_size >= ((size_t)6 << 20);   // 4.26 MB needed
    _Float16* ehs; float* esq_g; float* cand;
    if (use_ws) {                                 // scratch fully in d_ws
        char* wb = (char*)d_ws;
        ehs   = (_Float16*)wb;                    // 256 KB
        esq_g = (float*)(wb + (256u << 10));      // 4 KB
        cand  = (float*)(wb + (512u << 10));      // 4 MB
    } else {                                      // proven in-out layout
        char* ob = (char*)d_out;
        cand  = out;                              // [N][4] floats (4 MB)
        ehs   = (_Float16*)(ob + (32u << 20));
        esq_g = (float*)(ob + (36u << 20));
    }

    vq_prep<<<BINS / 256, 256, 0, stream>>>(embed, ehs, esq_g);
    vq_stage_a<<<N / 128, 256, 0, stream>>>(x, ehs, esq_g, cand);
    vq_rescore<<<N / 64, 256, 0, stream>>>(x, embed, esq_g, cand, ind_f,
                                           use_ws ? (float4*)out : nullptr);
    if (!use_ws)
        vq_gather<<<(N * (DIM / 4)) / 256, 256, 0, stream>>>(embed, ind_f, (float4*)out);
}

// Round 13
// 194.866 us; speedup vs baseline: 2.4458x; 1.1140x over previous
//
#include <hip/hip_runtime.h>

#define DIM  128
#define BINS 1024

typedef __attribute__((ext_vector_type(8))) _Float16 f16x8;
typedef __attribute__((ext_vector_type(4))) float f32x4;

#define MFMA16(a, b, c) __builtin_amdgcn_mfma_f32_16x16x32_f16(a, b, c, 0, 0, 0)

#define GLDS(gp, lp) __builtin_amdgcn_global_load_lds(                        \
    (const __attribute__((address_space(1))) void*)(gp),                     \
    (__attribute__((address_space(3))) void*)(lp), 16, 0, 0)

__device__ __forceinline__ float med3f(float a, float b, float c) {
#if __has_builtin(__builtin_amdgcn_fmed3f)
    return __builtin_amdgcn_fmed3f(a, b, c);
#else
    return fmaxf(fminf(a, b), fminf(fmaxf(a, b), c));
#endif
}

// sorted-insert x into descending (S0>=S1>=S2>=S3): 1 max + 3 med3, depth 2
#define SINS(x, S0, S1, S2, S3) do {                                          \
        float n0_ = fmaxf(S0, (x));                                           \
        float n1_ = med3f((x), S0, S1);                                       \
        float n2_ = med3f((x), S1, S2);                                       \
        float n3_ = med3f((x), S2, S3);                                       \
        S0 = n0_; S1 = n1_; S2 = n2_; S3 = n3_;                               \
    } while (0)

// pack bin id into low 10 mantissa bits of key (perturbation <= 0.016,
// absorbed by the candidate-margin budget; makes ordering bin-deterministic)
__device__ __forceinline__ float packkey(float k, int bin) {
    return __uint_as_float((__float_as_uint(k) & 0xFFFFFC00u) | (unsigned)bin);
}

// ---- prep: esq (round-1 1-chain fmaf, exact fp32) + E -> swizzled fp16 ----
__global__ __launch_bounds__(256) void vq_prep(
    const float* __restrict__ embed, _Float16* __restrict__ ehs,
    float* __restrict__ esq_g)
{
    int b = blockIdx.x * 256 + threadIdx.x;  // grid exactly BINS/256
    const float* e = embed + (size_t)b * DIM;
    float s = 0.f;
    #pragma unroll
    for (int k = 0; k < DIM; ++k) s = fmaf(e[k], e[k], s);
    esq_g[b] = s;
    #pragma unroll
    for (int c = 0; c < 16; ++c) {          // 16B chunks of the fp16 row
        int slot = c ^ (b & 15);            // XOR-swizzle baked into storage
        #pragma unroll
        for (int j = 0; j < 8; ++j)
            ehs[b * 128 + slot * 8 + j] = (_Float16)e[c * 8 + j];   // RNE
    }
}

// ---- stage A: 1-term fp16 MFMA approx + top-4 PAIR candidates ----
// 256 thr = 4 waves; wave owns 32 rows (2 rowsets). Swapped GEMM.
// D: col(lane&15)=x-row, row((lane>>4)*4+reg)=bin. key = 2*dot_h - esq.
// Fold: packed-key pair-max + sorted-insert float network (no index regs).
__global__ __launch_bounds__(256) void vq_stage_a(
    const float* __restrict__ x,
    const _Float16* __restrict__ ehs_g,
    const float* __restrict__ esq_g,
    float* __restrict__ cand)               // [N][4] candidate PAIR bases
{
    __shared__ _Float16 ehb[2][8192];       // 2 x 16 KB (64 bins x 128 fp16)
    __shared__ float esq_lds[BINS];         // 4 KB

    const int tid = threadIdx.x;
    const int li  = tid & 15;
    const int g   = (tid >> 4) & 3;
    const int w   = tid >> 6;

    // X fragments fp16 (rows rowA, rowA+16) — 32 VGPR, const-indexed
    f16x8 xh[2][4];
    const size_t rowA = (size_t)blockIdx.x * 128 + w * 32 + li;
    #pragma unroll
    for (int rs = 0; rs < 2; ++rs) {
        const float* xp = x + (rowA + rs * 16) * DIM + g * 8;
        #pragma unroll
        for (int s = 0; s < 4; ++s) {
            float4 v0 = *(const float4*)(xp + s * 32);
            float4 v1 = *(const float4*)(xp + s * 32 + 4);
            f16x8 h;
            h[0] = (_Float16)v0.x; h[1] = (_Float16)v0.y;
            h[2] = (_Float16)v0.z; h[3] = (_Float16)v0.w;
            h[4] = (_Float16)v1.x; h[5] = (_Float16)v1.y;
            h[6] = (_Float16)v1.z; h[7] = (_Float16)v1.w;
            xh[rs][s] = h;
        }
    }

#define STAGE(stp_, buf_) do {                                                \
        const char* gE_ = (const char*)ehs_g + (size_t)(stp_) * 16384;        \
        char* lE_ = (char*)&ehb[buf_][0];                                     \
        _Pragma("unroll")                                                     \
        for (int j_ = 0; j_ < 4; ++j_) {                                      \
            int o_ = tid * 16 + j_ * 4096;                                    \
            GLDS(gE_ + o_, lE_ + o_);                                         \
        }                                                                     \
    } while (0)

    // ---- prologue: esq + slab 0 ----
    GLDS((const char*)esq_g + tid * 16, (char*)esq_lds + tid * 16);
    STAGE(0, 0);
    asm volatile("s_waitcnt vmcnt(0)" ::: "memory");
    __syncthreads();

    // top-4 packed keys per rowset, descending
    const float NEG = __uint_as_float(0xFF7FFC00u);   // ~ -3.4e38, low bits 0
    float s0[2], s1[2], s2[2], s3[2];
    #pragma unroll
    for (int rs = 0; rs < 2; ++rs) { s0[rs] = s1[rs] = s2[rs] = s3[rs] = NEG; }

#define LDE(tl_, s_) (*(const f16x8*)((const char*)&ehb[buf][0] + (tl_) * 4096 + li * 256 + (((g + 4 * (s_)) ^ li) << 4)))

    for (int stp = 0; stp < 16; ++stp) {     // 16 steps x 64 bins
        const int buf = stp & 1;
        if (stp < 15) STAGE(stp + 1, buf ^ 1);   // prefetch next 64-bin slab

        #pragma unroll
        for (int tl = 0; tl < 4; ++tl) {
            f32x4 aP0 = {0.f,0.f,0.f,0.f}, aP1 = {0.f,0.f,0.f,0.f};
            f16x8 eh0 = LDE(tl, 0), eh1 = LDE(tl, 1);
            f16x8 eh2 = LDE(tl, 2), eh3 = LDE(tl, 3);
            aP0 = MFMA16(eh0, xh[0][0], aP0); aP1 = MFMA16(eh0, xh[1][0], aP1);
            aP0 = MFMA16(eh1, xh[0][1], aP0); aP1 = MFMA16(eh1, xh[1][1], aP1);
            aP0 = MFMA16(eh2, xh[0][2], aP0); aP1 = MFMA16(eh2, xh[1][2], aP1);
            aP0 = MFMA16(eh3, xh[0][3], aP0); aP1 = MFMA16(eh3, xh[1][3], aP1);
            // fold: key = 2*dot - esq, pack bin, pair-max, 2 sorted-inserts
            const int binb = stp * 64 + tl * 16 + g * 4;   // quad base
            const f32x4 eq = *(const f32x4*)&esq_lds[binb];
            {
                float p0 = packkey(fmaf(2.f, aP0[0], -eq[0]), binb + 0);
                float p1 = packkey(fmaf(2.f, aP0[1], -eq[1]), binb + 1);
                float p2 = packkey(fmaf(2.f, aP0[2], -eq[2]), binb + 2);
                float p3 = packkey(fmaf(2.f, aP0[3], -eq[3]), binb + 3);
                float pm01 = fmaxf(p0, p1), pm23 = fmaxf(p2, p3);
                SINS(pm01, s0[0], s1[0], s2[0], s3[0]);
                SINS(pm23, s0[0], s1[0], s2[0], s3[0]);
            }
            {
                float p0 = packkey(fmaf(2.f, aP1[0], -eq[0]), binb + 0);
                float p1 = packkey(fmaf(2.f, aP1[1], -eq[1]), binb + 1);
                float p2 = packkey(fmaf(2.f, aP1[2], -eq[2]), binb + 2);
                float p3 = packkey(fmaf(2.f, aP1[3], -eq[3]), binb + 3);
                float pm01 = fmaxf(p0, p1), pm23 = fmaxf(p2, p3);
                SINS(pm01, s0[1], s1[1], s2[1], s3[1]);
                SINS(pm23, s0[1], s1[1], s2[1], s3[1]);
            }
        }
        asm volatile("s_waitcnt vmcnt(0)" ::: "memory");
        __syncthreads();
    }
#undef LDE
#undef STAGE

    // ---- merge the 4 k-groups (disjoint pair sets, same rows) ----
    #pragma unroll
    for (int mm = 16; mm <= 32; mm <<= 1) {
        #pragma unroll
        for (int rs = 0; rs < 2; ++rs) {
            float q0 = __shfl_xor(s0[rs], mm);
            float q1 = __shfl_xor(s1[rs], mm);
            float q2 = __shfl_xor(s2[rs], mm);
            float q3 = __shfl_xor(s3[rs], mm);
            SINS(q0, s0[rs], s1[rs], s2[rs], s3[rs]);
            SINS(q1, s0[rs], s1[rs], s2[rs], s3[rs]);
            SINS(q2, s0[rs], s1[rs], s2[rs], s3[rs]);
            SINS(q3, s0[rs], s1[rs], s2[rs], s3[rs]);
        }
    }
    if ((tid & 63) < 16) {
        #pragma unroll
        for (int rs = 0; rs < 2; ++rs) {
            const size_t r = rowA + rs * 16;
            // unpack bin, emit pair base (bin & ~1) — r12 rescore interface
            cand[r * 4 + 0] = (float)(__float_as_uint(s0[rs]) & 1022u);
            cand[r * 4 + 1] = (float)(__float_as_uint(s1[rs]) & 1022u);
            cand[r * 4 + 2] = (float)(__float_as_uint(s2[rs]) & 1022u);
            cand[r * 4 + 3] = (float)(__float_as_uint(s3[rs]) & 1022u);
        }
    }
}

// ---- rescore: exact fp32 on 4 pairs (8 bins); k split across 4 lanes ----
// Lane sub owns k-chunks (j*4+sub)*4..+3 -> every e/x load is 64B-contiguous
// per 4-lane row-group. Butterfly shfl_xor sums are bitwise lane-identical.
// Optionally fuses the gather (outq != nullptr).  [proven round 12]
__global__ __launch_bounds__(256) void vq_rescore(
    const float* __restrict__ x, const float* __restrict__ embed,
    const float* __restrict__ esq_g, const float* __restrict__ cand,
    float* __restrict__ ind_f, float4* __restrict__ outq)
{
    const int tid = threadIdx.x;
    const int sub = tid & 3;
    const size_t row = (size_t)blockIdx.x * 64 + (tid >> 2);

    const float4* xg = (const float4*)(x + row * DIM);
    float4 xq[8];
    #pragma unroll
    for (int j = 0; j < 8; ++j) xq[j] = xg[j * 4 + sub];   // 64B/row-group

    float xs = 0.f;
    #pragma unroll
    for (int j = 0; j < 8; ++j) {
        float4 v = xq[j];
        xs = fmaf(v.x, v.x, xs); xs = fmaf(v.y, v.y, xs);
        xs = fmaf(v.z, v.z, xs); xs = fmaf(v.w, v.w, xs);
    }
    xs += __shfl_xor(xs, 1);
    xs += __shfl_xor(xs, 2);

    const float4 qv = *(const float4*)&cand[row * 4];
    const int qb0 = (int)qv.x, qb1 = (int)qv.y, qb2 = (int)qv.z, qb3 = (int)qv.w;

    const float4* e4 = (const float4*)embed;
    f32x4 acc[8];
    #pragma unroll
    for (int c = 0; c < 8; ++c) acc[c] = f32x4{0.f,0.f,0.f,0.f};
    #pragma unroll
    for (int c = 0; c < 8; ++c) {           // all 64 loads independent
        const int bin = (c < 2 ? qb0 : c < 4 ? qb1 : c < 6 ? qb2 : qb3) + (c & 1);
        #pragma unroll
        for (int j = 0; j < 8; ++j) {
            float4 ev = e4[(size_t)bin * 32 + j * 4 + sub];
            float4 xv = xq[j];
            acc[c][0] = fmaf(xv.x, ev.x, acc[c][0]);
            acc[c][1] = fmaf(xv.y, ev.y, acc[c][1]);
            acc[c][2] = fmaf(xv.z, ev.z, acc[c][2]);
            acc[c][3] = fmaf(xv.w, ev.w, acc[c][3]);
        }
    }
    float bd = -3.402823466e38f;
    int   bb = 0x7FFFFFFF;
    #pragma unroll
    for (int c = 0; c < 8; ++c) {
        const int bin = (c < 2 ? qb0 : c < 4 ? qb1 : c < 6 ? qb2 : qb3) + (c & 1);
        float p = (acc[c][0] + acc[c][1]) + (acc[c][2] + acc[c][3]);
        p += __shfl_xor(p, 1);
        p += __shfl_xor(p, 2);               // full dot, lane-identical
        float d = -(fmaf(-2.f, p, xs) + esq_g[bin]);   // round-1 expression
        if (d > bd || (d == bd && bin < bb)) { bd = d; bb = bin; }
    }
    if (sub == 0) ind_f[row] = (float)bb;
    if (outq) {                              // fused gather (all lanes agree on bb)
        #pragma unroll
        for (int j = 0; j < 8; ++j)
            outq[row * 32 + j * 4 + sub] = e4[(size_t)bb * 32 + j * 4 + sub];
    }
}

// ---- gather (fallback path only): quantize = embed[ind] ----
__global__ __launch_bounds__(256) void vq_gather(
    const float* __restrict__ embed,
    const float* __restrict__ ind_f,
    float4* __restrict__ out)
{
    int i   = blockIdx.x * 256 + threadIdx.x;   // over N*DIM/4
    int row = i >> 5;                           // DIM/4 == 32
    int k   = i & 31;
    int b   = (int)ind_f[row];
    out[i] = reinterpret_cast<const float4*>(embed)[b * (DIM / 4) + k];
}

extern "C" void kernel_launch(void* const* d_in, const int* in_sizes, int n_in,
                              void* d_out, int out_size, void* d_ws, size_t ws_size,
                              hipStream_t stream) {
    const float* x     = (const float*)d_in[0];   // [N, 128] fp32
    const float* embed = (const float*)d_in[1];   // [1024, 128] fp32
    float* out = (float*)d_out;

    const int N = in_sizes[0] / DIM;              // 262144
    float* ind_f = out + (size_t)N * DIM;         // output 1 (indices as float)

    const bool use_ws = ws_size >= ((size_t)6 << 20);   // 4.26 MB needed
    _Float16* ehs; float* esq_g; float* cand;
    if (use_ws) {                                 // scratch fully in d_ws
        char* wb = (char*)d_ws;
        ehs   = (_Float16*)wb;                    // 256 KB
        esq_g = (float*)(wb + (256u << 10));      // 4 KB
        cand  = (float*)(wb + (512u << 10));      // 4 MB
    } else {                                      // proven in-out layout
        char* ob = (char*)d_out;
        cand  = out;                              // [N][4] floats (4 MB)
        ehs   = (_Float16*)(ob + (32u << 20));
        esq_g = (float*)(ob + (36u << 20));
    }

    vq_prep<<<BINS / 256, 256, 0, stream>>>(embed, ehs, esq_g);
    vq_stage_a<<<N / 128, 256, 0, stream>>>(x, ehs, esq_g, cand);
    vq_rescore<<<N / 64, 256, 0, stream>>>(x, embed, esq_g, cand, ind_f,
                                           use_ws ? (float4*)out : nullptr);
    if (!use_ws)
        vq_gather<<<(N * (DIM / 4)) / 256, 256, 0, stream>>>(embed, ind_f, (float4*)out);
}

// Round 14
// 188.485 us; speedup vs baseline: 2.5286x; 1.0339x over previous
//
#include <hip/hip_runtime.h>

#define DIM  128
#define BINS 1024

typedef __attribute__((ext_vector_type(8))) _Float16 f16x8;
typedef __attribute__((ext_vector_type(4))) float f32x4;

#define MFMA16(a, b, c) __builtin_amdgcn_mfma_f32_16x16x32_f16(a, b, c, 0, 0, 0)

#define GLDS(gp, lp) __builtin_amdgcn_global_load_lds(                        \
    (const __attribute__((address_space(1))) void*)(gp),                     \
    (__attribute__((address_space(3))) void*)(lp), 16, 0, 0)

// guaranteed single-instruction v_med3_f32 (pattern-combine needs nnan flags)
__device__ __forceinline__ float med3a(float a, float b, float c) {
    float r;
    asm("v_med3_f32 %0, %1, %2, %3" : "=v"(r) : "v"(a), "v"(b), "v"(c));
    return r;
}

// guaranteed single-instruction v_and_or_b32: (key & mask) | bin
__device__ __forceinline__ float packkey(float k, int bin) {
    float r;
    asm("v_and_or_b32 %0, %1, %2, %3"
        : "=v"(r) : "v"(k), "s"(0xFFFFFC00u), "v"(bin));
    return r;
}

// sorted-insert x into descending (S0>=S1>=S2>=S3): 1 max + 3 med3, depth 2
#define SINS(x, S0, S1, S2, S3) do {                                          \
        float n0_ = fmaxf(S0, (x));                                           \
        float n1_ = med3a((x), S0, S1);                                       \
        float n2_ = med3a((x), S1, S2);                                       \
        float n3_ = med3a((x), S2, S3);                                       \
        S0 = n0_; S1 = n1_; S2 = n2_; S3 = n3_;                               \
    } while (0)

// ---- prep: esq (round-1 1-chain fmaf, exact fp32), cinit = -esq/2,
//      E -> swizzled fp16 table ----
__global__ __launch_bounds__(256) void vq_prep(
    const float* __restrict__ embed, _Float16* __restrict__ ehs,
    float* __restrict__ esq_g, float* __restrict__ cinit_g)
{
    int b = blockIdx.x * 256 + threadIdx.x;  // grid exactly BINS/256
    const float* e = embed + (size_t)b * DIM;
    float s = 0.f;
    #pragma unroll
    for (int k = 0; k < DIM; ++k) s = fmaf(e[k], e[k], s);
    esq_g[b] = s;
    cinit_g[b] = -0.5f * s;                  // MFMA C-init: key = dot - esq/2
    #pragma unroll
    for (int c = 0; c < 16; ++c) {          // 16B chunks of the fp16 row
        int slot = c ^ (b & 15);            // XOR-swizzle baked into storage
        #pragma unroll
        for (int j = 0; j < 8; ++j)
            ehs[b * 128 + slot * 8 + j] = (_Float16)e[c * 8 + j];   // RNE
    }
}

// ---- stage A: 1-term fp16 MFMA (C-init = -esq/2) + top-4 PAIR candidates ----
// 256 thr = 4 waves; wave owns 32 rows (2 rowsets). Swapped GEMM.
// D: col(lane&15)=x-row, row((lane>>4)*4+reg)=bin. MFMA out IS the key.
// Fold: v_and_or pack + pair-max + v_med3 sorted-insert (14 VALU/tile-rowset).
__global__ __launch_bounds__(256) void vq_stage_a(
    const float* __restrict__ x,
    const _Float16* __restrict__ ehs_g,
    const float* __restrict__ cinit_g,
    float* __restrict__ cand)               // [N][4] candidate PAIR bases
{
    __shared__ _Float16 ehb[2][8192];       // 2 x 16 KB (64 bins x 128 fp16)
    __shared__ float ci_lds[BINS];          // 4 KB (-esq/2)

    const int tid = threadIdx.x;
    const int li  = tid & 15;
    const int g   = (tid >> 4) & 3;
    const int w   = tid >> 6;

    // X fragments fp16 (rows rowA, rowA+16) — 32 VGPR, const-indexed
    f16x8 xh[2][4];
    const size_t rowA = (size_t)blockIdx.x * 128 + w * 32 + li;
    #pragma unroll
    for (int rs = 0; rs < 2; ++rs) {
        const float* xp = x + (rowA + rs * 16) * DIM + g * 8;
        #pragma unroll
        for (int s = 0; s < 4; ++s) {
            float4 v0 = *(const float4*)(xp + s * 32);
            float4 v1 = *(const float4*)(xp + s * 32 + 4);
            f16x8 h;
            h[0] = (_Float16)v0.x; h[1] = (_Float16)v0.y;
            h[2] = (_Float16)v0.z; h[3] = (_Float16)v0.w;
            h[4] = (_Float16)v1.x; h[5] = (_Float16)v1.y;
            h[6] = (_Float16)v1.z; h[7] = (_Float16)v1.w;
            xh[rs][s] = h;
        }
    }

#define STAGE(stp_, buf_) do {                                                \
        const char* gE_ = (const char*)ehs_g + (size_t)(stp_) * 16384;        \
        char* lE_ = (char*)&ehb[buf_][0];                                     \
        _Pragma("unroll")                                                     \
        for (int j_ = 0; j_ < 4; ++j_) {                                      \
            int o_ = tid * 16 + j_ * 4096;                                    \
            GLDS(gE_ + o_, lE_ + o_);                                         \
        }                                                                     \
    } while (0)

    // ---- prologue: cinit + slab 0 ----
    GLDS((const char*)cinit_g + tid * 16, (char*)ci_lds + tid * 16);
    STAGE(0, 0);
    asm volatile("s_waitcnt vmcnt(0)" ::: "memory");
    __syncthreads();

    // top-4 packed keys per rowset, descending
    const float NEG = __uint_as_float(0xFF7FFC00u);   // ~ -3.4e38, low bits 0
    float s0[2], s1[2], s2[2], s3[2];
    #pragma unroll
    for (int rs = 0; rs < 2; ++rs) { s0[rs] = s1[rs] = s2[rs] = s3[rs] = NEG; }

#define LDE(tl_, s_) (*(const f16x8*)((const char*)&ehb[buf][0] + (tl_) * 4096 + li * 256 + (((g + 4 * (s_)) ^ li) << 4)))

    for (int stp = 0; stp < 16; ++stp) {     // 16 steps x 64 bins
        const int buf = stp & 1;
        if (stp < 15) STAGE(stp + 1, buf ^ 1);   // prefetch next 64-bin slab

        #pragma unroll
        for (int tl = 0; tl < 4; ++tl) {
            const int binb = stp * 64 + tl * 16 + g * 4;   // quad base
            const f32x4 ci = *(const f32x4*)&ci_lds[binb];
            f16x8 eh0 = LDE(tl, 0), eh1 = LDE(tl, 1);
            f16x8 eh2 = LDE(tl, 2), eh3 = LDE(tl, 3);
            f32x4 aP0 = MFMA16(eh0, xh[0][0], ci);
            f32x4 aP1 = MFMA16(eh0, xh[1][0], ci);
            aP0 = MFMA16(eh1, xh[0][1], aP0); aP1 = MFMA16(eh1, xh[1][1], aP1);
            aP0 = MFMA16(eh2, xh[0][2], aP0); aP1 = MFMA16(eh2, xh[1][2], aP1);
            aP0 = MFMA16(eh3, xh[0][3], aP0); aP1 = MFMA16(eh3, xh[1][3], aP1);
            // fold: MFMA out is the key; pack bin, pair-max, 2 sorted-inserts
            {
                float p0 = packkey(aP0[0], binb + 0);
                float p1 = packkey(aP0[1], binb + 1);
                float p2 = packkey(aP0[2], binb + 2);
                float p3 = packkey(aP0[3], binb + 3);
                float pm01 = fmaxf(p0, p1), pm23 = fmaxf(p2, p3);
                SINS(pm01, s0[0], s1[0], s2[0], s3[0]);
                SINS(pm23, s0[0], s1[0], s2[0], s3[0]);
            }
            {
                float p0 = packkey(aP1[0], binb + 0);
                float p1 = packkey(aP1[1], binb + 1);
                float p2 = packkey(aP1[2], binb + 2);
                float p3 = packkey(aP1[3], binb + 3);
                float pm01 = fmaxf(p0, p1), pm23 = fmaxf(p2, p3);
                SINS(pm01, s0[1], s1[1], s2[1], s3[1]);
                SINS(pm23, s0[1], s1[1], s2[1], s3[1]);
            }
        }
        asm volatile("s_waitcnt vmcnt(0)" ::: "memory");
        __syncthreads();
    }
#undef LDE
#undef STAGE

    // ---- merge the 4 k-groups (disjoint pair sets, same rows) ----
    #pragma unroll
    for (int mm = 16; mm <= 32; mm <<= 1) {
        #pragma unroll
        for (int rs = 0; rs < 2; ++rs) {
            float q0 = __shfl_xor(s0[rs], mm);
            float q1 = __shfl_xor(s1[rs], mm);
            float q2 = __shfl_xor(s2[rs], mm);
            float q3 = __shfl_xor(s3[rs], mm);
            SINS(q0, s0[rs], s1[rs], s2[rs], s3[rs]);
            SINS(q1, s0[rs], s1[rs], s2[rs], s3[rs]);
            SINS(q2, s0[rs], s1[rs], s2[rs], s3[rs]);
            SINS(q3, s0[rs], s1[rs], s2[rs], s3[rs]);
        }
    }
    if ((tid & 63) < 16) {
        #pragma unroll
        for (int rs = 0; rs < 2; ++rs) {
            const size_t r = rowA + rs * 16;
            // unpack bin, emit pair base (bin & ~1) — r12 rescore interface
            cand[r * 4 + 0] = (float)(__float_as_uint(s0[rs]) & 1022u);
            cand[r * 4 + 1] = (float)(__float_as_uint(s1[rs]) & 1022u);
            cand[r * 4 + 2] = (float)(__float_as_uint(s2[rs]) & 1022u);
            cand[r * 4 + 3] = (float)(__float_as_uint(s3[rs]) & 1022u);
        }
    }
}

// ---- rescore: exact fp32 on 4 pairs (8 bins); k split across 4 lanes ----
// Lane sub owns k-chunks (j*4+sub)*4..+3 -> every e/x load is 64B-contiguous
// per 4-lane row-group. Butterfly shfl_xor sums are bitwise lane-identical.
// Optionally fuses the gather (outq != nullptr).  [proven round 12]
__global__ __launch_bounds__(256) void vq_rescore(
    const float* __restrict__ x, const float* __restrict__ embed,
    const float* __restrict__ esq_g, const float* __restrict__ cand,
    float* __restrict__ ind_f, float4* __restrict__ outq)
{
    const int tid = threadIdx.x;
    const int sub = tid & 3;
    const size_t row = (size_t)blockIdx.x * 64 + (tid >> 2);

    const float4* xg = (const float4*)(x + row * DIM);
    float4 xq[8];
    #pragma unroll
    for (int j = 0; j < 8; ++j) xq[j] = xg[j * 4 + sub];   // 64B/row-group

    float xs = 0.f;
    #pragma unroll
    for (int j = 0; j < 8; ++j) {
        float4 v = xq[j];
        xs = fmaf(v.x, v.x, xs); xs = fmaf(v.y, v.y, xs);
        xs = fmaf(v.z, v.z, xs); xs = fmaf(v.w, v.w, xs);
    }
    xs += __shfl_xor(xs, 1);
    xs += __shfl_xor(xs, 2);

    const float4 qv = *(const float4*)&cand[row * 4];
    const int qb0 = (int)qv.x, qb1 = (int)qv.y, qb2 = (int)qv.z, qb3 = (int)qv.w;

    const float4* e4 = (const float4*)embed;
    f32x4 acc[8];
    #pragma unroll
    for (int c = 0; c < 8; ++c) acc[c] = f32x4{0.f,0.f,0.f,0.f};
    #pragma unroll
    for (int c = 0; c < 8; ++c) {           // all 64 loads independent
        const int bin = (c < 2 ? qb0 : c < 4 ? qb1 : c < 6 ? qb2 : qb3) + (c & 1);
        #pragma unroll
        for (int j = 0; j < 8; ++j) {
            float4 ev = e4[(size_t)bin * 32 + j * 4 + sub];
            float4 xv = xq[j];
            acc[c][0] = fmaf(xv.x, ev.x, acc[c][0]);
            acc[c][1] = fmaf(xv.y, ev.y, acc[c][1]);
            acc[c][2] = fmaf(xv.z, ev.z, acc[c][2]);
            acc[c][3] = fmaf(xv.w, ev.w, acc[c][3]);
        }
    }
    float bd = -3.402823466e38f;
    int   bb = 0x7FFFFFFF;
    #pragma unroll
    for (int c = 0; c < 8; ++c) {
        const int bin = (c < 2 ? qb0 : c < 4 ? qb1 : c < 6 ? qb2 : qb3) + (c & 1);
        float p = (acc[c][0] + acc[c][1]) + (acc[c][2] + acc[c][3]);
        p += __shfl_xor(p, 1);
        p += __shfl_xor(p, 2);               // full dot, lane-identical
        float d = -(fmaf(-2.f, p, xs) + esq_g[bin]);   // round-1 expression
        if (d > bd || (d == bd && bin < bb)) { bd = d; bb = bin; }
    }
    if (sub == 0) ind_f[row] = (float)bb;
    if (outq) {                              // fused gather (all lanes agree on bb)
        #pragma unroll
        for (int j = 0; j < 8; ++j)
            outq[row * 32 + j * 4 + sub] = e4[(size_t)bb * 32 + j * 4 + sub];
    }
}

// ---- gather (fallback path only): quantize = embed[ind] ----
__global__ __launch_bounds__(256) void vq_gather(
    const float* __restrict__ embed,
    const float* __restrict__ ind_f,
    float4* __restrict__ out)
{
    int i   = blockIdx.x * 256 + threadIdx.x;   // over N*DIM/4
    int row = i >> 5;                           // DIM/4 == 32
    int k   = i & 31;
    int b   = (int)ind_f[row];
    out[i] = reinterpret_cast<const float4*>(embed)[b * (DIM / 4) + k];
}

extern "C" void kernel_launch(void* const* d_in, const int* in_sizes, int n_in,
                              void* d_out, int out_size, void* d_ws, size_t ws_size,
                              hipStream_t stream) {
    const float* x     = (const float*)d_in[0];   // [N, 128] fp32
    const float* embed = (const float*)d_in[1];   // [1024, 128] fp32
    float* out = (float*)d_out;

    const int N = in_sizes[0] / DIM;              // 262144
    float* ind_f = out + (size_t)N * DIM;         // output 1 (indices as float)

    const bool use_ws = ws_size >= ((size_t)6 << 20);   // 4.27 MB needed
    _Float16* ehs; float* esq_g; float* cinit_g; float* cand;
    if (use_ws) {                                 // scratch fully in d_ws
        char* wb = (char*)d_ws;
        ehs     = (_Float16*)wb;                  // 256 KB
        esq_g   = (float*)(wb + (256u << 10));    // 4 KB
        cinit_g = (float*)(wb + (260u << 10));    // 4 KB
        cand    = (float*)(wb + (512u << 10));    // 4 MB
    } else {                                      // proven in-out layout
        char* ob = (char*)d_out;
        cand    = out;                            // [N][4] floats (4 MB)
        ehs     = (_Float16*)(ob + (32u << 20));
        esq_g   = (float*)(ob + (36u << 20));
        cinit_g = (float*)(ob + (36u << 20) + 4096);
    }

    vq_prep<<<BINS / 256, 256, 0, stream>>>(embed, ehs, esq_g, cinit_g);
    vq_stage_a<<<N / 128, 256, 0, stream>>>(x, ehs, cinit_g, cand);
    vq_rescore<<<N / 64, 256, 0, stream>>>(x, embed, esq_g, cand, ind_f,
                                           use_ws ? (float4*)out : nullptr);
    if (!use_ws)
        vq_gather<<<(N * (DIM / 4)) / 256, 256, 0, stream>>>(embed, ind_f, (float4*)out);
}